// Round 17
// baseline (246.308 us; speedup 1.0000x reference)
//
#include <hip/hip_runtime.h>

#define NCH 256
#define HID 16
#define NBLK 256       // block b handles graphs A=b, B=b+256
#define SREG 16        // f32x4 direct-load stash slots/thread (64 regs) — proven
// A: [loA, loA+256) regs + [loA+256, loA+512) LDS bf16
// B: [loB, loB+256) regs + [loB+256, loB+512) LDS bf16 (s_stash reused)

typedef __attribute__((ext_vector_type(4))) float f32x4;
typedef __attribute__((ext_vector_type(4))) unsigned int u32x4;

__device__ __forceinline__ f32x4 ldrow(const float* __restrict__ x, int r, size_t coff) {
    return *reinterpret_cast<const f32x4*>(x + (size_t)r * NCH + coff);
}

__device__ __forceinline__ void strow(float* __restrict__ out, int r, size_t coff, f32x4 v) {
    __builtin_nontemporal_store(v, reinterpret_cast<f32x4*>(out + (size_t)r * NCH + coff));
}

__device__ __forceinline__ u32x4 packrow(f32x4 a, f32x4 b) {
    u32x4 ua = __builtin_bit_cast(u32x4, a) + 0x8000u;
    u32x4 ub = __builtin_bit_cast(u32x4, b) + 0x8000u;
    return (ua & 0xffff0000u) | (ub >> 16);
}
__device__ __forceinline__ f32x4 unhi(u32x4 p) { return __builtin_bit_cast(f32x4, p & 0xffff0000u); }
__device__ __forceinline__ f32x4 unlo(u32x4 p) { return __builtin_bit_cast(f32x4, p << 16); }

__device__ __forceinline__ void se_mlp(const float* __restrict__ W1,
                                       const float* __restrict__ W2,
                                       float (&s_part)[16][NCH], int cnt,
                                       float* __restrict__ s_vec,
                                       float (&s_hp)[HID][17], float (&s_h)[HID],
                                       int tid)
{
    if (tid < NCH) {
        float m = 0.f;
        #pragma unroll
        for (int i = 0; i < 16; ++i) m += s_part[i][tid];
        m *= (cnt > 0) ? (1.0f / (float)cnt) : 1.0f;
        s_vec[tid] = m;
    }
    __syncthreads();
    if (tid < NCH) {
        const int j = tid >> 4, sub = tid & 15;
        float hp = 0.f;
        #pragma unroll
        for (int i = 0; i < 16; ++i) { int c = sub * 16 + i; hp += s_vec[c] * W1[c * HID + j]; }
        s_hp[j][sub] = hp;
    }
    __syncthreads();
    if (tid < HID) {
        float h = 0.f;
        #pragma unroll
        for (int i = 0; i < 16; ++i) h += s_hp[tid][i];
        s_h[tid] = fmaxf(h, 0.f);
    }
    __syncthreads();
    if (tid < NCH) {
        float sc = 0.f;
        #pragma unroll
        for (int j = 0; j < HID; ++j) sc += s_h[j] * W2[j * NCH + tid];
        s_vec[tid] = 1.0f / (1.0f + __expf(-sc));
    }
}

__global__ __launch_bounds__(1024, 4) void graph_se_kernel(
    const float* __restrict__ x,
    const int* __restrict__ batch,
    const float* __restrict__ W1,
    const float* __restrict__ W2,
    float* __restrict__ out,
    int n)
{
    const int b   = blockIdx.x;
    const int tid = threadIdx.x;

    __shared__ unsigned int s_stash[128][NCH];   // 128 KiB bf16-packed (A then B)
    __shared__ int   s_bnd[4];
    __shared__ float s_part[16][NCH];
    __shared__ float s_vecA[NCH];
    __shared__ float s_vecB[NCH];
    __shared__ float s_hp[HID][17];
    __shared__ float s_h[HID];

    if (tid < 4) {
        int v = (tid < 2) ? (b + tid) : (NBLK + b + (tid - 2));
        int lo = 0, hi = n;
        while (lo < hi) { int mid = (lo + hi) >> 1; if (batch[mid] < v) lo = mid + 1; else hi = mid; }
        s_bnd[tid] = lo;
    }
    __syncthreads();
    const int loA = s_bnd[0], hiA = s_bnd[1];
    const int loB = s_bnd[2], hiB = s_bnd[3];

    const int rg = tid >> 6;            // wave 0..15
    const int c4 = tid & 63;
    const size_t coff = (size_t)c4 * 4;

    f32x4 st[SREG];                     // static-indexed only

    const int ldsA  = loA + 256;        // A-LDS stash rows [loA+256, loA+512)
    const int tailA = loA + 512;
    const int ldsB  = loB + 256;        // B-LDS stash rows [loB+256, loB+512)
    const int tailB = loB + 512;

    // ---- P1: pool A; 256 rows -> regs, 256 -> LDS bf16, tail ----
    {
        f32x4 acc = (f32x4)(0.f);
        #pragma unroll
        for (int j = 0; j < SREG; ++j) {
            int r0 = loA + rg + 16 * j;
            if (r0 < hiA) { st[j] = ldrow(x, r0, coff); acc += st[j]; }
        }
        #pragma unroll 2
        for (int k = 0; k < 8; ++k) {
            int i  = rg + 16 * k;              // slots 0..127
            int r0 = ldsA + i, r1 = r0 + 128;
            f32x4 v0 = (f32x4)(0.f), v1 = (f32x4)(0.f);
            if (r0 < hiA) { v0 = ldrow(x, r0, coff); acc += v0; }
            if (r1 < hiA) { v1 = ldrow(x, r1, coff); acc += v1; }
            *reinterpret_cast<u32x4*>(&s_stash[i][c4 * 4]) = packrow(v0, v1);
        }
        int r = tailA + rg;
        for (; r + 48 < hiA; r += 64) {
            f32x4 v0 = ldrow(x, r     , coff);
            f32x4 v1 = ldrow(x, r + 16, coff);
            f32x4 v2 = ldrow(x, r + 32, coff);
            f32x4 v3 = ldrow(x, r + 48, coff);
            acc += (v0 + v1) + (v2 + v3);
        }
        for (; r < hiA; r += 16) acc += ldrow(x, r, coff);
        *reinterpret_cast<f32x4*>(&s_part[rg][c4 * 4]) = acc;
    }
    __syncthreads();

    se_mlp(W1, W2, s_part, hiA - loA, s_vecA, s_hp, s_h, tid);
    __syncthreads();

    const f32x4 scvA = *reinterpret_cast<const f32x4*>(&s_vecA[c4 * 4]);

    // ---- P3: write A-reg stash (st dies), then role split ----
    #pragma unroll
    for (int j = 0; j < SREG; ++j) {
        int rA = loA + rg + 16 * j;
        if (rA < hiA) strow(out, rA, coff, st[j] * scvA);
    }
    if (rg < 8) {
        // writers: A-LDS writeback (frees own slots), A tail, then B stashes
        #pragma unroll 2
        for (int k = 0; k < 16; ++k) {
            int i  = rg + 8 * k;               // slots 0..127 (own slots)
            u32x4 p = *reinterpret_cast<const u32x4*>(&s_stash[i][c4 * 4]);
            int r0 = ldsA + i, r1 = r0 + 128;
            if (r0 < hiA) strow(out, r0, coff, unhi(p) * scvA);
            if (r1 < hiA) strow(out, r1, coff, unlo(p) * scvA);
        }
        int r = tailA + rg;
        for (; r + 24 < hiA; r += 32) {
            f32x4 v0 = ldrow(x, r     , coff);
            f32x4 v1 = ldrow(x, r +  8, coff);
            f32x4 v2 = ldrow(x, r + 16, coff);
            f32x4 v3 = ldrow(x, r + 24, coff);
            strow(out, r     , coff, v0 * scvA);
            strow(out, r +  8, coff, v1 * scvA);
            strow(out, r + 16, coff, v2 * scvA);
            strow(out, r + 24, coff, v3 * scvA);
        }
        for (; r < hiA; r += 8) strow(out, r, coff, ldrow(x, r, coff) * scvA);
        // B reg stash [loB+128, loB+256)
        f32x4 accB = (f32x4)(0.f);
        #pragma unroll
        for (int j = 0; j < SREG; ++j) {
            int rB = loB + 128 + rg + 8 * j;
            if (rB < hiB) { st[j] = ldrow(x, rB, coff); accB += st[j]; }
        }
        // B LDS stash [loB+256, loB+512) into own (now-free) slots
        #pragma unroll 2
        for (int k = 0; k < 16; ++k) {
            int i  = rg + 8 * k;
            int r0 = ldsB + i, r1 = r0 + 128;
            f32x4 v0 = (f32x4)(0.f), v1 = (f32x4)(0.f);
            if (r0 < hiB) { v0 = ldrow(x, r0, coff); accB += v0; }
            if (r1 < hiB) { v1 = ldrow(x, r1, coff); accB += v1; }
            *reinterpret_cast<u32x4*>(&s_stash[i][c4 * 4]) = packrow(v0, v1);
        }
        *reinterpret_cast<f32x4*>(&s_part[rg][c4 * 4]) = accB;
    } else {
        // pool waves: B reg stash [loB, loB+128) + B tail from loB+512
        const int gid = rg - 8;
        f32x4 accB = (f32x4)(0.f);
        #pragma unroll
        for (int j = 0; j < SREG; ++j) {
            int rB = loB + gid + 8 * j;
            if (rB < hiB) { st[j] = ldrow(x, rB, coff); accB += st[j]; }
        }
        int r = tailB + gid;
        for (; r + 24 < hiB; r += 32) {
            f32x4 v0 = ldrow(x, r     , coff);
            f32x4 v1 = ldrow(x, r +  8, coff);
            f32x4 v2 = ldrow(x, r + 16, coff);
            f32x4 v3 = ldrow(x, r + 24, coff);
            accB += (v0 + v1) + (v2 + v3);
        }
        for (; r < hiB; r += 8) accB += ldrow(x, r, coff);
        *reinterpret_cast<f32x4*>(&s_part[rg][c4 * 4]) = accB;
    }
    __syncthreads();

    se_mlp(W1, W2, s_part, hiB - loB, s_vecB, s_hp, s_h, tid);
    __syncthreads();

    // ---- P5: write all B stashes + B tail ----
    {
        const f32x4 scvB = *reinterpret_cast<const f32x4*>(&s_vecB[c4 * 4]);
        if (rg < 8) {
            // writers: B reg stash + B LDS stash
            #pragma unroll
            for (int j = 0; j < SREG; ++j) {
                int rB = loB + 128 + rg + 8 * j;
                if (rB < hiB) strow(out, rB, coff, st[j] * scvB);
            }
            #pragma unroll 2
            for (int k = 0; k < 16; ++k) {
                int i  = rg + 8 * k;
                u32x4 p = *reinterpret_cast<const u32x4*>(&s_stash[i][c4 * 4]);
                int r0 = ldsB + i, r1 = r0 + 128;
                if (r0 < hiB) strow(out, r0, coff, unhi(p) * scvB);
                if (r1 < hiB) strow(out, r1, coff, unlo(p) * scvB);
            }
        } else {
            const int gid = rg - 8;
            #pragma unroll
            for (int j = 0; j < SREG; ++j) {
                int rB = loB + gid + 8 * j;
                if (rB < hiB) strow(out, rB, coff, st[j] * scvB);
            }
            // B tail: read + write
            int r = tailB + gid;
            for (; r + 24 < hiB; r += 32) {
                f32x4 v0 = ldrow(x, r     , coff);
                f32x4 v1 = ldrow(x, r +  8, coff);
                f32x4 v2 = ldrow(x, r + 16, coff);
                f32x4 v3 = ldrow(x, r + 24, coff);
                strow(out, r     , coff, v0 * scvB);
                strow(out, r +  8, coff, v1 * scvB);
                strow(out, r + 16, coff, v2 * scvB);
                strow(out, r + 24, coff, v3 * scvB);
            }
            for (; r < hiB; r += 8) strow(out, r, coff, ldrow(x, r, coff) * scvB);
        }
    }
}

extern "C" void kernel_launch(void* const* d_in, const int* in_sizes, int n_in,
                              void* d_out, int out_size, void* d_ws, size_t ws_size,
                              hipStream_t stream) {
    const float* x     = (const float*)d_in[0];
    const int*   batch = (const int*)d_in[1];
    const float* W1    = (const float*)d_in[2];
    const float* W2    = (const float*)d_in[3];
    float*       out   = (float*)d_out;
    const int n = in_sizes[1];

    hipLaunchKernelGGL(graph_se_kernel, dim3(NBLK), dim3(1024), 0, stream,
                       x, batch, W1, W2, out, n);
}

// Round 18
// 244.075 us; speedup vs baseline: 1.0091x; 1.0091x over previous
//
#include <hip/hip_runtime.h>

#define NCH 256
#define HID 16
#define NBLK 256       // block b handles graphs A=b, B=b+256
#define SREG 16        // f32x4 direct-load stash slots/thread (64 regs) — proven
// A: [loA, loA+256) regs + [loA+256, loA+512) LDS bf16 (256 rows packed)
// B: [loB, loB+128) pool-wave regs + [loB+128, loB+256) writer-wave regs

typedef __attribute__((ext_vector_type(4))) float f32x4;
typedef __attribute__((ext_vector_type(4))) unsigned int u32x4;

__device__ __forceinline__ f32x4 ldrow(const float* __restrict__ x, int r, size_t coff) {
    return *reinterpret_cast<const f32x4*>(x + (size_t)r * NCH + coff);
}

__device__ __forceinline__ void strow(float* __restrict__ out, int r, size_t coff, f32x4 v) {
    __builtin_nontemporal_store(v, reinterpret_cast<f32x4*>(out + (size_t)r * NCH + coff));
}

__device__ __forceinline__ u32x4 packrow(f32x4 a, f32x4 b) {
    u32x4 ua = __builtin_bit_cast(u32x4, a) + 0x8000u;
    u32x4 ub = __builtin_bit_cast(u32x4, b) + 0x8000u;
    return (ua & 0xffff0000u) | (ub >> 16);
}
__device__ __forceinline__ f32x4 unhi(u32x4 p) { return __builtin_bit_cast(f32x4, p & 0xffff0000u); }
__device__ __forceinline__ f32x4 unlo(u32x4 p) { return __builtin_bit_cast(f32x4, p << 16); }

__device__ __forceinline__ void se_mlp(const float* __restrict__ W1,
                                       const float* __restrict__ W2,
                                       float (&s_part)[16][NCH], int cnt,
                                       float* __restrict__ s_vec,
                                       float (&s_hp)[HID][17], float (&s_h)[HID],
                                       int tid)
{
    if (tid < NCH) {
        float m = 0.f;
        #pragma unroll
        for (int i = 0; i < 16; ++i) m += s_part[i][tid];
        m *= (cnt > 0) ? (1.0f / (float)cnt) : 1.0f;
        s_vec[tid] = m;
    }
    __syncthreads();
    if (tid < NCH) {
        const int j = tid >> 4, sub = tid & 15;
        float hp = 0.f;
        #pragma unroll
        for (int i = 0; i < 16; ++i) { int c = sub * 16 + i; hp += s_vec[c] * W1[c * HID + j]; }
        s_hp[j][sub] = hp;
    }
    __syncthreads();
    if (tid < HID) {
        float h = 0.f;
        #pragma unroll
        for (int i = 0; i < 16; ++i) h += s_hp[tid][i];
        s_h[tid] = fmaxf(h, 0.f);
    }
    __syncthreads();
    if (tid < NCH) {
        float sc = 0.f;
        #pragma unroll
        for (int j = 0; j < HID; ++j) sc += s_h[j] * W2[j * NCH + tid];
        s_vec[tid] = 1.0f / (1.0f + __expf(-sc));
    }
}

__global__ __launch_bounds__(1024, 4) void graph_se_kernel(
    const float* __restrict__ x,
    const int* __restrict__ batch,
    const float* __restrict__ W1,
    const float* __restrict__ W2,
    float* __restrict__ out,
    int n)
{
    const int b   = blockIdx.x;
    const int tid = threadIdx.x;

    __shared__ unsigned int s_stash[128][NCH];   // 128 KiB: 256 A-rows bf16-packed
    __shared__ int   s_bnd[4];
    __shared__ float s_part[16][NCH];
    __shared__ float s_vecA[NCH];
    __shared__ float s_vecB[NCH];
    __shared__ float s_hp[HID][17];
    __shared__ float s_h[HID];

    if (tid < 4) {
        int v = (tid < 2) ? (b + tid) : (NBLK + b + (tid - 2));
        int lo = 0, hi = n;
        while (lo < hi) { int mid = (lo + hi) >> 1; if (batch[mid] < v) lo = mid + 1; else hi = mid; }
        s_bnd[tid] = lo;
    }
    __syncthreads();
    const int loA = s_bnd[0], hiA = s_bnd[1];
    const int loB = s_bnd[2], hiB = s_bnd[3];

    const int rg = tid >> 6;            // wave 0..15
    const int c4 = tid & 63;
    const size_t coff = (size_t)c4 * 4;

    f32x4 st[SREG];                     // static-indexed only

    const int ldsA  = loA + 16 * SREG;  // LDS-stash start (loA+256)
    const int tailA = ldsA + 256;       // unstashed A start (loA+512)
    const int tailB = loB + 256;        // unstashed B start

    // ---- P1: pool A; 256 rows -> regs (f32 direct), 256 -> LDS (bf16) ----
    {
        f32x4 acc = (f32x4)(0.f);
        #pragma unroll
        for (int j = 0; j < SREG; ++j) {
            int r0 = loA + rg + 16 * j;
            if (r0 < hiA) { st[j] = ldrow(x, r0, coff); acc += st[j]; }
        }
        #pragma unroll 2
        for (int k = 0; k < 8; ++k) {
            int i  = rg + 16 * k;              // 0..127
            int r0 = ldsA + i, r1 = r0 + 128;
            f32x4 v0 = (f32x4)(0.f), v1 = (f32x4)(0.f);
            if (r0 < hiA) { v0 = ldrow(x, r0, coff); acc += v0; }
            if (r1 < hiA) { v1 = ldrow(x, r1, coff); acc += v1; }
            *reinterpret_cast<u32x4*>(&s_stash[i][c4 * 4]) = packrow(v0, v1);
        }
        int r = tailA + rg;
        for (; r + 48 < hiA; r += 64) {
            f32x4 v0 = ldrow(x, r     , coff);
            f32x4 v1 = ldrow(x, r + 16, coff);
            f32x4 v2 = ldrow(x, r + 32, coff);
            f32x4 v3 = ldrow(x, r + 48, coff);
            acc += (v0 + v1) + (v2 + v3);
        }
        for (; r < hiA; r += 16) acc += ldrow(x, r, coff);
        *reinterpret_cast<f32x4*>(&s_part[rg][c4 * 4]) = acc;
    }
    __syncthreads();

    se_mlp(W1, W2, s_part, hiA - loA, s_vecA, s_hp, s_h, tid);
    __syncthreads();

    const f32x4 scvA = *reinterpret_cast<const f32x4*>(&s_vecA[c4 * 4]);

    // ---- P3: all waves write A-reg stash (st dies), then role split ----
    #pragma unroll
    for (int j = 0; j < SREG; ++j) {
        int rA = loA + rg + 16 * j;
        if (rA < hiA) strow(out, rA, coff, st[j] * scvA);
    }
    if (rg < 8) {
        // writers: A-LDS stash writeback + A tail, then stash B second half
        #pragma unroll 2
        for (int k = 0; k < 16; ++k) {
            int i  = rg + 8 * k;               // 0..127
            u32x4 p = *reinterpret_cast<const u32x4*>(&s_stash[i][c4 * 4]);
            int r0 = ldsA + i, r1 = r0 + 128;
            if (r0 < hiA) strow(out, r0, coff, unhi(p) * scvA);
            if (r1 < hiA) strow(out, r1, coff, unlo(p) * scvA);
        }
        int r = tailA + rg;
        for (; r + 24 < hiA; r += 32) {
            f32x4 v0 = ldrow(x, r     , coff);
            f32x4 v1 = ldrow(x, r +  8, coff);
            f32x4 v2 = ldrow(x, r + 16, coff);
            f32x4 v3 = ldrow(x, r + 24, coff);
            strow(out, r     , coff, v0 * scvA);
            strow(out, r +  8, coff, v1 * scvA);
            strow(out, r + 16, coff, v2 * scvA);
            strow(out, r + 24, coff, v3 * scvA);
        }
        for (; r < hiA; r += 8) strow(out, r, coff, ldrow(x, r, coff) * scvA);
        // B-stash rows [loB+128, loB+256)
        f32x4 accB = (f32x4)(0.f);
        #pragma unroll
        for (int j = 0; j < SREG; ++j) {
            int rB = loB + 128 + rg + 8 * j;
            if (rB < hiB) { st[j] = ldrow(x, rB, coff); accB += st[j]; }
        }
        *reinterpret_cast<f32x4*>(&s_part[rg][c4 * 4]) = accB;
    } else {
        // pool waves: B-stash rows [loB, loB+128) + B tail
        const int gid = rg - 8;
        f32x4 accB = (f32x4)(0.f);
        #pragma unroll
        for (int j = 0; j < SREG; ++j) {
            int rB = loB + gid + 8 * j;
            if (rB < hiB) { st[j] = ldrow(x, rB, coff); accB += st[j]; }
        }
        int r = tailB + gid;
        for (; r + 24 < hiB; r += 32) {
            f32x4 v0 = ldrow(x, r     , coff);
            f32x4 v1 = ldrow(x, r +  8, coff);
            f32x4 v2 = ldrow(x, r + 16, coff);
            f32x4 v3 = ldrow(x, r + 24, coff);
            accB += (v0 + v1) + (v2 + v3);
        }
        for (; r < hiB; r += 8) accB += ldrow(x, r, coff);
        *reinterpret_cast<f32x4*>(&s_part[rg][c4 * 4]) = accB;
    }
    __syncthreads();

    se_mlp(W1, W2, s_part, hiB - loB, s_vecB, s_hp, s_h, tid);
    __syncthreads();

    // ---- P5: write B stash (both halves) + B tail ----
    {
        const f32x4 scvB = *reinterpret_cast<const f32x4*>(&s_vecB[c4 * 4]);
        if (rg < 8) {
            #pragma unroll
            for (int j = 0; j < SREG; ++j) {
                int rB = loB + 128 + rg + 8 * j;
                if (rB < hiB) strow(out, rB, coff, st[j] * scvB);
            }
        } else {
            const int gid = rg - 8;
            #pragma unroll
            for (int j = 0; j < SREG; ++j) {
                int rB = loB + gid + 8 * j;
                if (rB < hiB) strow(out, rB, coff, st[j] * scvB);
            }
        }
        int r = tailB + rg;
        for (; r + 48 < hiB; r += 64) {
            f32x4 v0 = ldrow(x, r     , coff);
            f32x4 v1 = ldrow(x, r + 16, coff);
            f32x4 v2 = ldrow(x, r + 32, coff);
            f32x4 v3 = ldrow(x, r + 48, coff);
            strow(out, r     , coff, v0 * scvB);
            strow(out, r + 16, coff, v1 * scvB);
            strow(out, r + 32, coff, v2 * scvB);
            strow(out, r + 48, coff, v3 * scvB);
        }
        for (; r < hiB; r += 16) strow(out, r, coff, ldrow(x, r, coff) * scvB);
    }
}

extern "C" void kernel_launch(void* const* d_in, const int* in_sizes, int n_in,
                              void* d_out, int out_size, void* d_ws, size_t ws_size,
                              hipStream_t stream) {
    const float* x     = (const float*)d_in[0];
    const int*   batch = (const int*)d_in[1];
    const float* W1    = (const float*)d_in[2];
    const float* W2    = (const float*)d_in[3];
    float*       out   = (float*)d_out;
    const int n = in_sizes[1];

    hipLaunchKernelGGL(graph_se_kernel, dim3(NBLK), dim3(1024), 0, stream,
                       x, batch, W1, W2, out, n);
}